// Round 1
// baseline (1990.602 us; speedup 1.0000x reference)
//
#include <hip/hip_runtime.h>
#include <math.h>

#define EPS 1e-5f

// ---------------------------------------------------------------------------
// block reduction: 256 threads (4 waves of 64). Returns total on all threads.
__device__ __forceinline__ float block_reduce_sum_256(float v, float* red) {
    #pragma unroll
    for (int o = 32; o > 0; o >>= 1) v += __shfl_down(v, o, 64);
    __syncthreads();                       // protect red[] from previous use
    if ((threadIdx.x & 63) == 0) red[threadIdx.x >> 6] = v;
    __syncthreads();
    return red[0] + red[1] + red[2] + red[3];
}

// ---------------------------------------------------------------------------
// FiLM: gb[bt,1024] = z[bt,:] @ film_w[32,1024] + film_b
__global__ __launch_bounds__(256) void film_kernel(
    const float* __restrict__ z, const float* __restrict__ fw,
    const float* __restrict__ fb, float* __restrict__ gb) {
    int bt = blockIdx.x;
    __shared__ float zs[32];
    if (threadIdx.x < 32) zs[threadIdx.x] = z[bt * 32 + threadIdx.x];
    __syncthreads();
    for (int j = threadIdx.x; j < 1024; j += 256) {
        float acc = fb[j];
        #pragma unroll
        for (int k = 0; k < 32; k++) acc = fmaf(zs[k], fw[k * 1024 + j], acc);
        gb[bt * 1024 + j] = acc;
    }
}

// ---------------------------------------------------------------------------
// conv weight transpose: w[512][576] -> wT[576][512]
__global__ __launch_bounds__(256) void wt_kernel(
    const float* __restrict__ w, float* __restrict__ wT) {
    __shared__ float tile[32][33];
    int kx = blockIdx.x * 32;   // k base (576/32 = 18)
    int dx = blockIdx.y * 32;   // d base (512/32 = 16)
    int lx = threadIdx.x & 31, ly = threadIdx.x >> 5;   // 32 x 8
    #pragma unroll
    for (int i = 0; i < 32; i += 8)
        tile[ly + i][lx] = w[(size_t)(dx + ly + i) * 576 + kx + lx];
    __syncthreads();
    #pragma unroll
    for (int i = 0; i < 32; i += 8)
        wT[(size_t)(kx + ly + i) * 512 + dx + lx] = tile[lx][ly + i];
}

// ---------------------------------------------------------------------------
// Fused tokenizer: causal conv3d + LN + FiLM + spatial mean.
// 1 block per (b,t). 64 spatial tokens in 4 batches of 16. 256 threads,
// each thread owns output channels d0=tid, d1=tid+256.
__global__ __launch_bounds__(256) void conv_tok_kernel(
    const float* __restrict__ x, const float* __restrict__ wT,
    const float* __restrict__ cb, const float* __restrict__ tg,
    const float* __restrict__ tb, const float* __restrict__ gb,
    float* __restrict__ h) {
    __shared__ float patch[16 * 576];
    __shared__ float red[8];
    int bt = blockIdx.x, b = bt >> 5, t = bt & 31;
    int tid = threadIdx.x;
    float cb0 = cb[tid], cb1 = cb[tid + 256];
    float tg0 = tg[tid], tb0 = tb[tid];
    float tg1 = tg[tid + 256], tb1 = tb[tid + 256];
    float g0 = 1.f + 0.5f * gb[bt * 1024 + tid];
    float g1 = 1.f + 0.5f * gb[bt * 1024 + tid + 256];
    float be0 = 0.5f * gb[bt * 1024 + 512 + tid];
    float be1 = 0.5f * gb[bt * 1024 + 512 + tid + 256];
    float hacc0 = 0.f, hacc1 = 0.f;

    for (int batch = 0; batch < 4; batch++) {
        // stage 16 patches (16 x 576 floats)
        for (int idx = tid; idx < 16 * 576; idx += 256) {
            int j = idx / 576, k = idx - j * 576;
            int n = batch * 16 + j;
            int hn = n >> 3, wn = n & 7;
            int c = k / 192;
            int r = k - c * 192;
            int kt = r >> 6, rr = r & 63;
            int ph = rr >> 3, pw = rr & 7;
            int tt = t + kt - 2;
            float v = 0.f;
            if (tt >= 0)
                v = x[(((size_t)(b * 32 + tt) * 3 + c) * 64 + (hn * 8 + ph)) * 64
                      + (wn * 8 + pw)];
            patch[idx] = v;
        }
        __syncthreads();

        float a0[16], a1[16];
        #pragma unroll
        for (int j = 0; j < 16; j++) { a0[j] = cb0; a1[j] = cb1; }

        for (int k = 0; k < 576; k += 4) {
            const float* wp = wT + (size_t)k * 512 + tid;
            float w00 = wp[0],    w01 = wp[512],  w02 = wp[1024], w03 = wp[1536];
            float w10 = wp[256],  w11 = wp[768],  w12 = wp[1280], w13 = wp[1792];
            #pragma unroll
            for (int j = 0; j < 16; j++) {
                const float4 p = *(const float4*)&patch[j * 576 + k];
                a0[j] = fmaf(p.x, w00, a0[j]);
                a0[j] = fmaf(p.y, w01, a0[j]);
                a0[j] = fmaf(p.z, w02, a0[j]);
                a0[j] = fmaf(p.w, w03, a0[j]);
                a1[j] = fmaf(p.x, w10, a1[j]);
                a1[j] = fmaf(p.y, w11, a1[j]);
                a1[j] = fmaf(p.z, w12, a1[j]);
                a1[j] = fmaf(p.w, w13, a1[j]);
            }
        }

        // per-token LN + FiLM + accumulate spatial mean
        for (int j = 0; j < 16; j++) {
            float s  = block_reduce_sum_256(a0[j] + a1[j], red);
            float ss = block_reduce_sum_256(a0[j] * a0[j] + a1[j] * a1[j], red);
            float mu = s * (1.f / 512.f);
            float var = ss * (1.f / 512.f) - mu * mu;
            float inv = rsqrtf(var + EPS);
            float v0 = (a0[j] - mu) * inv * tg0 + tb0;
            float v1 = (a1[j] - mu) * inv * tg1 + tb1;
            v0 = g0 * v0 + be0;
            v1 = g1 * v1 + be1;
            hacc0 += v0;
            hacc1 += v1;
        }
        __syncthreads();
    }
    h[bt * 512 + tid]       = hacc0 * (1.f / 64.f);
    h[bt * 512 + tid + 256] = hacc1 * (1.f / 64.f);
}

// ---------------------------------------------------------------------------
// LayerNorm over D=512. 1 block per token.
__global__ __launch_bounds__(256) void ln_kernel(
    const float* __restrict__ in, const float* __restrict__ g,
    const float* __restrict__ bb, float* __restrict__ out) {
    __shared__ float red[8];
    int token = blockIdx.x, tid = threadIdx.x;
    float v0 = in[token * 512 + tid], v1 = in[token * 512 + tid + 256];
    float s  = block_reduce_sum_256(v0 + v1, red);
    float ss = block_reduce_sum_256(v0 * v0 + v1 * v1, red);
    float mu = s * (1.f / 512.f);
    float var = ss * (1.f / 512.f) - mu * mu;
    float inv = rsqrtf(var + EPS);
    out[token * 512 + tid]       = (v0 - mu) * inv * g[tid] + bb[tid];
    out[token * 512 + tid + 256] = (v1 - mu) * inv * g[tid + 256] + bb[tid + 256];
}

// ---------------------------------------------------------------------------
// Generic fp32 GEMM: out[M,N] = epi(A[M,K] @ B[K,N] + bias).
// Tile 32(M) x 64(N), k-step 16. act: 0=none, 1=exact GELU.
// If res != nullptr: out = res + (*resScale) * val.
__global__ __launch_bounds__(256) void gemm_kernel(
    const float* __restrict__ A, const float* __restrict__ B,
    const float* __restrict__ bias, const float* __restrict__ res,
    const float* __restrict__ resScale, float* __restrict__ out,
    int M, int N, int K, int act) {
    __shared__ float As[16][33];
    __shared__ float Bs[16][68];
    int bx = blockIdx.x, by = blockIdx.y;
    int tid = threadIdx.x;
    int tx = tid & 15, ty = tid >> 4;
    int m0 = by * 32, n0 = bx * 64;
    float acc[2][4] = {{0.f, 0.f, 0.f, 0.f}, {0.f, 0.f, 0.f, 0.f}};

    for (int k0 = 0; k0 < K; k0 += 16) {
        #pragma unroll
        for (int l = 0; l < 2; l++) {
            int idx = l * 256 + tid;
            int m = idx >> 4, kk = idx & 15;
            As[kk][m] = A[(size_t)(m0 + m) * K + k0 + kk];
        }
        #pragma unroll
        for (int l = 0; l < 4; l++) {
            int idx = l * 256 + tid;
            int kk = idx >> 6, n = idx & 63;
            Bs[kk][n] = B[(size_t)(k0 + kk) * N + n0 + n];
        }
        __syncthreads();
        #pragma unroll
        for (int kk = 0; kk < 16; kk++) {
            float a0 = As[kk][ty * 2];
            float a1 = As[kk][ty * 2 + 1];
            float4 bv = *(const float4*)&Bs[kk][tx * 4];
            acc[0][0] = fmaf(a0, bv.x, acc[0][0]);
            acc[0][1] = fmaf(a0, bv.y, acc[0][1]);
            acc[0][2] = fmaf(a0, bv.z, acc[0][2]);
            acc[0][3] = fmaf(a0, bv.w, acc[0][3]);
            acc[1][0] = fmaf(a1, bv.x, acc[1][0]);
            acc[1][1] = fmaf(a1, bv.y, acc[1][1]);
            acc[1][2] = fmaf(a1, bv.z, acc[1][2]);
            acc[1][3] = fmaf(a1, bv.w, acc[1][3]);
        }
        __syncthreads();
    }

    float rs = resScale ? *resScale : 0.f;
    #pragma unroll
    for (int i = 0; i < 2; i++) {
        int m = m0 + ty * 2 + i;
        #pragma unroll
        for (int j = 0; j < 4; j++) {
            int n = n0 + tx * 4 + j;
            float v = acc[i][j] + bias[n];
            if (act == 1) v = 0.5f * v * (1.f + erff(v * 0.70710678118f));
            if (res) v = res[(size_t)m * N + n] + rs * v;
            out[(size_t)m * N + n] = v;
        }
    }
}

// ---------------------------------------------------------------------------
// Attention for one (b, head). T=32, DH=64, causal, RoPE on q,k.
// kqv layout [token][1536] with chunk order k,q,v.
__global__ __launch_bounds__(256) void attn_kernel(
    const float* __restrict__ kqv, float* __restrict__ yv) {
    __shared__ float qs[32][64], ks[32][64], vs[32][64];
    __shared__ float qr[32][64], kr[32][64];
    __shared__ float att[32][32];
    int blk = blockIdx.x;
    int b = blk >> 3, hh = blk & 7;
    int tid = threadIdx.x;

    for (int idx = tid; idx < 2048; idx += 256) {
        int t = idx >> 6, d = idx & 63;
        const float* base = kqv + (size_t)(b * 32 + t) * 1536 + hh * 64 + d;
        ks[t][d] = base[0];
        qs[t][d] = base[512];
        vs[t][d] = base[1024];
    }
    __syncthreads();
    // RoPE
    const float lnb = logf(10000.f) / 32.f;
    for (int idx = tid; idx < 2048; idx += 256) {
        int t = idx >> 6, d = idx & 63;
        int j = d & 31;
        float ang = (float)t * expf(-(float)j * lnb);
        float sv = sinf(ang), cv = cosf(ang);
        float qv = qs[t][d], kv = ks[t][d];
        float qo = qs[t][d ^ 32], ko = ks[t][d ^ 32];
        float rq = (d < 32) ? -qo : qo;
        float rk = (d < 32) ? -ko : ko;
        qr[t][d] = qv * cv + rq * sv;
        kr[t][d] = kv * cv + rk * sv;
    }
    __syncthreads();
    // scores (1024, 4 per thread), causal mask, scale 1/sqrt(64)
    #pragma unroll
    for (int l = 0; l < 4; l++) {
        int idx = l * 256 + tid;
        int qt = idx >> 5, kt2 = idx & 31;
        float s;
        if (kt2 > qt) {
            s = -1e30f;
        } else {
            float acc = 0.f;
            #pragma unroll
            for (int d = 0; d < 64; d++) acc = fmaf(qr[qt][d], kr[kt2][d], acc);
            s = acc * 0.125f;
        }
        att[qt][kt2] = s;
    }
    __syncthreads();
    if (tid < 32) {
        float m = -1e30f;
        #pragma unroll
        for (int k = 0; k < 32; k++) m = fmaxf(m, att[tid][k]);
        float sum = 0.f;
        #pragma unroll
        for (int k = 0; k < 32; k++) {
            float e = expf(att[tid][k] - m);
            att[tid][k] = e;
            sum += e;
        }
        float inv = 1.f / sum;
        #pragma unroll
        for (int k = 0; k < 32; k++) att[tid][k] *= inv;
    }
    __syncthreads();
    for (int idx = tid; idx < 2048; idx += 256) {
        int t = idx >> 6, d = idx & 63;
        float acc = 0.f;
        #pragma unroll
        for (int k = 0; k < 32; k++) acc = fmaf(att[t][k], vs[k][d], acc);
        yv[(size_t)(b * 32 + t) * 512 + hh * 64 + d] = acc;
    }
}

// ---------------------------------------------------------------------------
// head: LN(h) . head_w + head_bias -> out[token]
__global__ __launch_bounds__(256) void head_kernel(
    const float* __restrict__ h, const float* __restrict__ g,
    const float* __restrict__ bb, const float* __restrict__ w,
    const float* __restrict__ bias0, float* __restrict__ out) {
    __shared__ float red[8];
    int token = blockIdx.x, tid = threadIdx.x;
    float v0 = h[token * 512 + tid], v1 = h[token * 512 + tid + 256];
    float s  = block_reduce_sum_256(v0 + v1, red);
    float ss = block_reduce_sum_256(v0 * v0 + v1 * v1, red);
    float mu = s * (1.f / 512.f);
    float var = ss * (1.f / 512.f) - mu * mu;
    float inv = rsqrtf(var + EPS);
    float n0 = (v0 - mu) * inv * g[tid] + bb[tid];
    float n1 = (v1 - mu) * inv * g[tid + 256] + bb[tid + 256];
    float dot = block_reduce_sum_256(n0 * w[tid] + n1 * w[tid + 256], red);
    if (tid == 0) out[token] = dot + bias0[0];
}

// ---------------------------------------------------------------------------
extern "C" void kernel_launch(void* const* d_in, const int* in_sizes, int n_in,
                              void* d_out, int out_size, void* d_ws, size_t ws_size,
                              hipStream_t stream) {
    const float* x       = (const float*)d_in[0];
    const float* z       = (const float*)d_in[1];
    const float* conv_w  = (const float*)d_in[2];
    const float* conv_b  = (const float*)d_in[3];
    const float* tok_g   = (const float*)d_in[4];
    const float* tok_b   = (const float*)d_in[5];
    const float* film_w  = (const float*)d_in[6];
    const float* film_b  = (const float*)d_in[7];
    const float* ln1_g   = (const float*)d_in[8];
    const float* ln1_b   = (const float*)d_in[9];
    const float* kqv_w   = (const float*)d_in[10];
    const float* kqv_b   = (const float*)d_in[11];
    const float* proj_w  = (const float*)d_in[12];
    const float* proj_b  = (const float*)d_in[13];
    const float* ln2_g   = (const float*)d_in[14];
    const float* ln2_b   = (const float*)d_in[15];
    const float* mlp_w1  = (const float*)d_in[16];
    const float* mlp_b1  = (const float*)d_in[17];
    const float* mlp_w2  = (const float*)d_in[18];
    const float* mlp_b2  = (const float*)d_in[19];
    const float* rs_attn = (const float*)d_in[20];
    const float* rs_mlp  = (const float*)d_in[21];
    const float* head_g  = (const float*)d_in[22];
    const float* head_b  = (const float*)d_in[23];
    const float* head_w  = (const float*)d_in[24];
    const float* head_bs = (const float*)d_in[25];
    float* out = (float*)d_out;

    float* ws   = (float*)d_ws;
    float* wT   = ws;                 // 576*512           = 294912
    float* gb   = wT + 294912;        // 512*1024          = 524288
    float* h    = gb + 524288;        // 512*512           = 262144
    float* xbuf = h + 262144;         // 512*512           = 262144
    float* kqvb = xbuf + 262144;      // 512*1536          = 786432
    float* yvb  = kqvb + 786432;      // 512*512           = 262144
    float* mbuf = yvb + 262144;       // 512*2048          = 1048576
    // total 3,440,640 floats = 13.76 MB

    film_kernel<<<512, 256, 0, stream>>>(z, film_w, film_b, gb);
    wt_kernel<<<dim3(18, 16), 256, 0, stream>>>(conv_w, wT);
    conv_tok_kernel<<<512, 256, 0, stream>>>(x, wT, conv_b, tok_g, tok_b, gb, h);

    for (int i = 0; i < 6; i++) {
        ln_kernel<<<512, 256, 0, stream>>>(h, ln1_g + i * 512, ln1_b + i * 512, xbuf);
        gemm_kernel<<<dim3(1536 / 64, 512 / 32), 256, 0, stream>>>(
            xbuf, kqv_w + (size_t)i * 512 * 1536, kqv_b + i * 1536,
            nullptr, nullptr, kqvb, 512, 1536, 512, 0);
        attn_kernel<<<128, 256, 0, stream>>>(kqvb, yvb);
        gemm_kernel<<<dim3(512 / 64, 512 / 32), 256, 0, stream>>>(
            yvb, proj_w + (size_t)i * 512 * 512, proj_b + i * 512,
            h, rs_attn + i, h, 512, 512, 512, 0);
        ln_kernel<<<512, 256, 0, stream>>>(h, ln2_g + i * 512, ln2_b + i * 512, xbuf);
        gemm_kernel<<<dim3(2048 / 64, 512 / 32), 256, 0, stream>>>(
            xbuf, mlp_w1 + (size_t)i * 512 * 2048, mlp_b1 + i * 2048,
            nullptr, nullptr, mbuf, 512, 2048, 512, 1);
        gemm_kernel<<<dim3(512 / 64, 512 / 32), 256, 0, stream>>>(
            mbuf, mlp_w2 + (size_t)i * 2048 * 512, mlp_b2 + i * 512,
            h, rs_mlp + i, h, 512, 512, 2048, 0);
    }

    head_kernel<<<512, 256, 0, stream>>>(h, head_g, head_b, head_w, head_bs, out);
}

// Round 2
// 1041.652 us; speedup vs baseline: 1.9110x; 1.9110x over previous
//
#include <hip/hip_runtime.h>
#include <math.h>

#define EPS 1e-5f

typedef __attribute__((ext_vector_type(8))) short short8;
typedef __attribute__((ext_vector_type(4))) float f32x4;

// fp32 -> bf16 round-to-nearest-even
__device__ __forceinline__ short f2bf(float f) {
    unsigned u = __float_as_uint(f);
    u += 0x7fffu + ((u >> 16) & 1u);
    return (short)(u >> 16);
}

// ---------------------------------------------------------------------------
__device__ __forceinline__ float block_reduce_sum_256(float v, float* red) {
    #pragma unroll
    for (int o = 32; o > 0; o >>= 1) v += __shfl_down(v, o, 64);
    __syncthreads();
    if ((threadIdx.x & 63) == 0) red[threadIdx.x >> 6] = v;
    __syncthreads();
    return red[0] + red[1] + red[2] + red[3];
}

// ---------------------------------------------------------------------------
// FiLM: gb[bt,1024] = z[bt,:] @ film_w[32,1024] + film_b
__global__ __launch_bounds__(256) void film_kernel(
    const float* __restrict__ z, const float* __restrict__ fw,
    const float* __restrict__ fb, float* __restrict__ gb) {
    int bt = blockIdx.x;
    __shared__ float zs[32];
    if (threadIdx.x < 32) zs[threadIdx.x] = z[bt * 32 + threadIdx.x];
    __syncthreads();
    for (int j = threadIdx.x; j < 1024; j += 256) {
        float acc = fb[j];
        #pragma unroll
        for (int k = 0; k < 32; k++) acc = fmaf(zs[k], fw[k * 1024 + j], acc);
        gb[bt * 1024 + j] = acc;
    }
}

// ---------------------------------------------------------------------------
// elementwise fp32 -> bf16 cast (conv weights: already [N=512][K=576] layout)
__global__ __launch_bounds__(256) void cvt_kernel(
    const float* __restrict__ src, short* __restrict__ dst, int n) {
    int i = blockIdx.x * 256 + threadIdx.x;
    if (i < n) dst[i] = f2bf(src[i]);
}

// ---------------------------------------------------------------------------
// Fused tokenizer via MFMA: causal conv3d (as GEMM) + LN + FiLM + spatial mean.
// 1 block per (b,t). M=64 spatial tokens, N=512 channels, K=576.
// 4 waves, wave w owns channels [w*128, w*128+128): 4 m-tiles x 8 n-tiles.
__global__ __launch_bounds__(256) void conv_tok_mfma(
    const float* __restrict__ x, const short* __restrict__ wbf,
    const float* __restrict__ cb, const float* __restrict__ tg,
    const float* __restrict__ tb, const float* __restrict__ gb,
    float* __restrict__ h) {
    __shared__ short Asl[64 * 40];    // 64 tokens x 32 k, pad 40
    __shared__ short Bsl[512 * 40];   // 512 n x 32 k, pad 40
    __shared__ float redsum[4][64], redss[4][64];
    __shared__ float mu_s[64], inv_s[64];
    int bt = blockIdx.x, b = bt >> 5, t = bt & 31;
    int tid = threadIdx.x;
    int wave = tid >> 6, lane = tid & 63, quad = lane >> 4, l16 = lane & 15;

    f32x4 acc[4][8];
    #pragma unroll
    for (int mt = 0; mt < 4; mt++)
        #pragma unroll
        for (int nt = 0; nt < 8; nt++) acc[mt][nt] = (f32x4){0.f, 0.f, 0.f, 0.f};

    for (int k0 = 0; k0 < 576; k0 += 32) {
        // stage A: im2col patch chunk, 64 tokens x 32 k
        #pragma unroll
        for (int e = 0; e < 8; e++) {
            int idx = e * 256 + tid;
            int m = idx >> 5, kk = idx & 31;
            int k = k0 + kk;
            int c = k / 192, r = k - c * 192;
            int kt = r >> 6, rr = r & 63;
            int tt = t + kt - 2;
            float v = 0.f;
            if (tt >= 0)
                v = x[(((size_t)(b * 32 + tt) * 3 + c) << 12)
                      + ((m >> 3) * 8 + (rr >> 3)) * 64 + (m & 7) * 8 + (rr & 7)];
            Asl[m * 40 + kk] = f2bf(v);
        }
        // stage B: 512 rows x 32 k bf16, int4 (16B) loads
        #pragma unroll
        for (int e = 0; e < 8; e++) {
            int idx = e * 256 + tid;
            int n = idx >> 2, seg = idx & 3;
            *(int4*)&Bsl[n * 40 + seg * 8] =
                *(const int4*)(wbf + (size_t)n * 576 + k0 + seg * 8);
        }
        __syncthreads();
        short8 af[4];
        #pragma unroll
        for (int mt = 0; mt < 4; mt++)
            af[mt] = *(const short8*)&Asl[(mt * 16 + l16) * 40 + quad * 8];
        #pragma unroll
        for (int nt = 0; nt < 8; nt++) {
            short8 bfr = *(const short8*)&Bsl[(wave * 128 + nt * 16 + l16) * 40 + quad * 8];
            #pragma unroll
            for (int mt = 0; mt < 4; mt++)
                acc[mt][nt] = __builtin_amdgcn_mfma_f32_16x16x32_bf16(
                    af[mt], bfr, acc[mt][nt], 0, 0, 0);
        }
        __syncthreads();
    }

    // epilogue: per-token LN over 512 channels + FiLM + spatial mean
    float cbn[8], tgn[8], tbn[8], gn[8], ben[8];
    #pragma unroll
    for (int nt = 0; nt < 8; nt++) {
        int n = wave * 128 + nt * 16 + l16;
        cbn[nt] = cb[n]; tgn[nt] = tg[n]; tbn[nt] = tb[n];
        gn[nt]  = 1.f + 0.5f * gb[bt * 1024 + n];
        ben[nt] = 0.5f * gb[bt * 1024 + 512 + n];
    }
    #pragma unroll
    for (int mt = 0; mt < 4; mt++)
        #pragma unroll
        for (int reg = 0; reg < 4; reg++) {
            float s = 0.f, ss = 0.f;
            #pragma unroll
            for (int nt = 0; nt < 8; nt++) {
                float v = acc[mt][nt][reg] + cbn[nt];
                s += v; ss += v * v;
            }
            #pragma unroll
            for (int o = 1; o < 16; o <<= 1) {
                s  += __shfl_xor(s, o, 64);
                ss += __shfl_xor(ss, o, 64);
            }
            if (l16 == 0) {
                int m = mt * 16 + quad * 4 + reg;
                redsum[wave][m] = s; redss[wave][m] = ss;
            }
        }
    __syncthreads();
    if (tid < 64) {
        float S  = redsum[0][tid] + redsum[1][tid] + redsum[2][tid] + redsum[3][tid];
        float SS = redss[0][tid] + redss[1][tid] + redss[2][tid] + redss[3][tid];
        float mu = S * (1.f / 512.f);
        float var = SS * (1.f / 512.f) - mu * mu;
        mu_s[tid] = mu; inv_s[tid] = rsqrtf(var + EPS);
    }
    __syncthreads();
    float hsum[8] = {0.f, 0.f, 0.f, 0.f, 0.f, 0.f, 0.f, 0.f};
    #pragma unroll
    for (int mt = 0; mt < 4; mt++)
        #pragma unroll
        for (int reg = 0; reg < 4; reg++) {
            int m = mt * 16 + quad * 4 + reg;
            float mu = mu_s[m], inv = inv_s[m];
            #pragma unroll
            for (int nt = 0; nt < 8; nt++) {
                float v = acc[mt][nt][reg] + cbn[nt];
                hsum[nt] += (v - mu) * inv * tgn[nt] + tbn[nt];
            }
        }
    #pragma unroll
    for (int nt = 0; nt < 8; nt++) {
        hsum[nt] += __shfl_xor(hsum[nt], 16, 64);
        hsum[nt] += __shfl_xor(hsum[nt], 32, 64);
    }
    if (quad == 0)
        #pragma unroll
        for (int nt = 0; nt < 8; nt++) {
            int n = wave * 128 + nt * 16 + l16;
            h[bt * 512 + n] = gn[nt] * (hsum[nt] * (1.f / 64.f)) + ben[nt];
        }
}

// ---------------------------------------------------------------------------
// LayerNorm over D=512, bf16 output. 1 block per token.
__global__ __launch_bounds__(256) void ln_bf16_kernel(
    const float* __restrict__ in, const float* __restrict__ g,
    const float* __restrict__ bb, short* __restrict__ out) {
    __shared__ float red[8];
    int token = blockIdx.x, tid = threadIdx.x;
    float v0 = in[token * 512 + tid], v1 = in[token * 512 + tid + 256];
    float s  = block_reduce_sum_256(v0 + v1, red);
    float ss = block_reduce_sum_256(v0 * v0 + v1 * v1, red);
    float mu = s * (1.f / 512.f);
    float var = ss * (1.f / 512.f) - mu * mu;
    float inv = rsqrtf(var + EPS);
    out[token * 512 + tid]       = f2bf((v0 - mu) * inv * g[tid] + bb[tid]);
    out[token * 512 + tid + 256] = f2bf((v1 - mu) * inv * g[tid + 256] + bb[tid + 256]);
}

// ---------------------------------------------------------------------------
// bf16 MFMA GEMM: out[M,N] = epi(A[M,K](bf16) @ B[K,N](fp32, cast on the fly)).
// 64x64 tile, 4 waves (2x2 of 32x32 per wave => 2x2 16x16 MFMA tiles each).
// act: 0=none, 1=exact GELU. res: out = res + (*resScale)*val.
// outf (fp32) and/or outb (bf16) may be null.
__global__ __launch_bounds__(256) void gemm_mfma(
    const short* __restrict__ A, const float* __restrict__ Bsrc,
    const float* __restrict__ bias, const float* __restrict__ res,
    const float* __restrict__ resScale, float* __restrict__ outf,
    short* __restrict__ outb, int M, int N, int K, int act) {
    __shared__ short Asl[64 * 40];
    __shared__ short Bsl[64 * 40];
    int tid = threadIdx.x;
    int n0 = blockIdx.x * 64, m0 = blockIdx.y * 64;
    int wave = tid >> 6, lane = tid & 63, quad = lane >> 4, l16 = lane & 15;
    int mw = wave & 1, nw = wave >> 1;
    f32x4 acc[2][2];
    #pragma unroll
    for (int mt = 0; mt < 2; mt++)
        #pragma unroll
        for (int nt = 0; nt < 2; nt++) acc[mt][nt] = (f32x4){0.f, 0.f, 0.f, 0.f};

    int r = tid >> 2, seg = tid & 3;
    for (int k0 = 0; k0 < K; k0 += 32) {
        // A: bf16, 16B vector loads
        *(int4*)&Asl[r * 40 + seg * 8] =
            *(const int4*)(A + (size_t)(m0 + r) * K + k0 + seg * 8);
        // B: fp32 [K][N] -> transpose+cast into Bsl[n][k]
        #pragma unroll
        for (int e = 0; e < 8; e++) {
            int idx = e * 256 + tid;
            int kk = idx >> 6, nn = idx & 63;
            Bsl[nn * 40 + kk] = f2bf(Bsrc[(size_t)(k0 + kk) * N + n0 + nn]);
        }
        __syncthreads();
        short8 af[2], bfr[2];
        #pragma unroll
        for (int mt = 0; mt < 2; mt++)
            af[mt] = *(const short8*)&Asl[(mw * 32 + mt * 16 + l16) * 40 + quad * 8];
        #pragma unroll
        for (int nt = 0; nt < 2; nt++)
            bfr[nt] = *(const short8*)&Bsl[(nw * 32 + nt * 16 + l16) * 40 + quad * 8];
        #pragma unroll
        for (int mt = 0; mt < 2; mt++)
            #pragma unroll
            for (int nt = 0; nt < 2; nt++)
                acc[mt][nt] = __builtin_amdgcn_mfma_f32_16x16x32_bf16(
                    af[mt], bfr[nt], acc[mt][nt], 0, 0, 0);
        __syncthreads();
    }

    float rs = resScale ? *resScale : 0.f;
    #pragma unroll
    for (int mt = 0; mt < 2; mt++)
        #pragma unroll
        for (int nt = 0; nt < 2; nt++)
            #pragma unroll
            for (int reg = 0; reg < 4; reg++) {
                int m = m0 + mw * 32 + mt * 16 + quad * 4 + reg;
                int n = n0 + nw * 32 + nt * 16 + l16;
                float v = acc[mt][nt][reg] + bias[n];
                if (act == 1) v = 0.5f * v * (1.f + erff(v * 0.70710678118f));
                if (res) v = res[(size_t)m * N + n] + rs * v;
                if (outf) outf[(size_t)m * N + n] = v;
                if (outb) outb[(size_t)m * N + n] = f2bf(v);
            }
}

// ---------------------------------------------------------------------------
// Attention for one (b, head). T=32, DH=64, causal, RoPE. bf16 output.
__global__ __launch_bounds__(256) void attn_kernel(
    const float* __restrict__ kqv, short* __restrict__ yv) {
    __shared__ float qs[32][64], ks[32][64], vs[32][64];
    __shared__ float qr[32][64], kr[32][64];
    __shared__ float att[32][32];
    int blk = blockIdx.x;
    int b = blk >> 3, hh = blk & 7;
    int tid = threadIdx.x;

    for (int idx = tid; idx < 2048; idx += 256) {
        int t = idx >> 6, d = idx & 63;
        const float* base = kqv + (size_t)(b * 32 + t) * 1536 + hh * 64 + d;
        ks[t][d] = base[0];
        qs[t][d] = base[512];
        vs[t][d] = base[1024];
    }
    __syncthreads();
    const float lnb = logf(10000.f) / 32.f;
    for (int idx = tid; idx < 2048; idx += 256) {
        int t = idx >> 6, d = idx & 63;
        int j = d & 31;
        float ang = (float)t * expf(-(float)j * lnb);
        float sv = sinf(ang), cv = cosf(ang);
        float qv = qs[t][d], kv = ks[t][d];
        float qo = qs[t][d ^ 32], ko = ks[t][d ^ 32];
        float rq = (d < 32) ? -qo : qo;
        float rk = (d < 32) ? -ko : ko;
        qr[t][d] = qv * cv + rq * sv;
        kr[t][d] = kv * cv + rk * sv;
    }
    __syncthreads();
    #pragma unroll
    for (int l = 0; l < 4; l++) {
        int idx = l * 256 + tid;
        int qt = idx >> 5, kt2 = idx & 31;
        float s;
        if (kt2 > qt) {
            s = -1e30f;
        } else {
            float a = 0.f;
            #pragma unroll
            for (int d = 0; d < 64; d++) a = fmaf(qr[qt][d], kr[kt2][d], a);
            s = a * 0.125f;
        }
        att[qt][kt2] = s;
    }
    __syncthreads();
    if (tid < 32) {
        float m = -1e30f;
        #pragma unroll
        for (int k = 0; k < 32; k++) m = fmaxf(m, att[tid][k]);
        float sum = 0.f;
        #pragma unroll
        for (int k = 0; k < 32; k++) {
            float e = expf(att[tid][k] - m);
            att[tid][k] = e;
            sum += e;
        }
        float inv = 1.f / sum;
        #pragma unroll
        for (int k = 0; k < 32; k++) att[tid][k] *= inv;
    }
    __syncthreads();
    for (int idx = tid; idx < 2048; idx += 256) {
        int t = idx >> 6, d = idx & 63;
        float a = 0.f;
        #pragma unroll
        for (int k = 0; k < 32; k++) a = fmaf(att[t][k], vs[k][d], a);
        yv[(size_t)(b * 32 + t) * 512 + hh * 64 + d] = f2bf(a);
    }
}

// ---------------------------------------------------------------------------
__global__ __launch_bounds__(256) void head_kernel(
    const float* __restrict__ h, const float* __restrict__ g,
    const float* __restrict__ bb, const float* __restrict__ w,
    const float* __restrict__ bias0, float* __restrict__ out) {
    __shared__ float red[8];
    int token = blockIdx.x, tid = threadIdx.x;
    float v0 = h[token * 512 + tid], v1 = h[token * 512 + tid + 256];
    float s  = block_reduce_sum_256(v0 + v1, red);
    float ss = block_reduce_sum_256(v0 * v0 + v1 * v1, red);
    float mu = s * (1.f / 512.f);
    float var = ss * (1.f / 512.f) - mu * mu;
    float inv = rsqrtf(var + EPS);
    float n0 = (v0 - mu) * inv * g[tid] + bb[tid];
    float n1 = (v1 - mu) * inv * g[tid + 256] + bb[tid + 256];
    float dot = block_reduce_sum_256(n0 * w[tid] + n1 * w[tid + 256], red);
    if (tid == 0) out[token] = dot + bias0[0];
}

// ---------------------------------------------------------------------------
extern "C" void kernel_launch(void* const* d_in, const int* in_sizes, int n_in,
                              void* d_out, int out_size, void* d_ws, size_t ws_size,
                              hipStream_t stream) {
    const float* x       = (const float*)d_in[0];
    const float* z       = (const float*)d_in[1];
    const float* conv_w  = (const float*)d_in[2];
    const float* conv_b  = (const float*)d_in[3];
    const float* tok_g   = (const float*)d_in[4];
    const float* tok_b   = (const float*)d_in[5];
    const float* film_w  = (const float*)d_in[6];
    const float* film_b  = (const float*)d_in[7];
    const float* ln1_g   = (const float*)d_in[8];
    const float* ln1_b   = (const float*)d_in[9];
    const float* kqv_w   = (const float*)d_in[10];
    const float* kqv_b   = (const float*)d_in[11];
    const float* proj_w  = (const float*)d_in[12];
    const float* proj_b  = (const float*)d_in[13];
    const float* ln2_g   = (const float*)d_in[14];
    const float* ln2_b   = (const float*)d_in[15];
    const float* mlp_w1  = (const float*)d_in[16];
    const float* mlp_b1  = (const float*)d_in[17];
    const float* mlp_w2  = (const float*)d_in[18];
    const float* mlp_b2  = (const float*)d_in[19];
    const float* rs_attn = (const float*)d_in[20];
    const float* rs_mlp  = (const float*)d_in[21];
    const float* head_g  = (const float*)d_in[22];
    const float* head_b  = (const float*)d_in[23];
    const float* head_w  = (const float*)d_in[24];
    const float* head_bs = (const float*)d_in[25];
    float* out = (float*)d_out;

    float* ws   = (float*)d_ws;
    float* gb   = ws;                  // 512*1024 = 524288 f
    float* h    = gb + 524288;         // 512*512  = 262144 f
    float* kqvb = h + 262144;          // 512*1536 = 786432 f
    short* wbf     = (short*)(kqvb + 786432);   // 294912 sh = 147456 f
    short* xbuf_bf = wbf + 294912;              // 512*512 sh = 131072 f
    short* yv_bf   = xbuf_bf + 262144;          // 512*512 sh = 131072 f
    short* mbuf_bf = yv_bf + 262144;            // 512*2048 sh = 524288 f
    // total ~2.5M floats = 10 MB

    film_kernel<<<512, 256, 0, stream>>>(z, film_w, film_b, gb);
    cvt_kernel<<<1152, 256, 0, stream>>>(conv_w, wbf, 294912);
    conv_tok_mfma<<<512, 256, 0, stream>>>(x, wbf, conv_b, tok_g, tok_b, gb, h);

    for (int i = 0; i < 6; i++) {
        ln_bf16_kernel<<<512, 256, 0, stream>>>(h, ln1_g + i * 512, ln1_b + i * 512, xbuf_bf);
        gemm_mfma<<<dim3(24, 8), 256, 0, stream>>>(
            xbuf_bf, kqv_w + (size_t)i * 512 * 1536, kqv_b + i * 1536,
            nullptr, nullptr, kqvb, nullptr, 512, 1536, 512, 0);
        attn_kernel<<<128, 256, 0, stream>>>(kqvb, yv_bf);
        gemm_mfma<<<dim3(8, 8), 256, 0, stream>>>(
            yv_bf, proj_w + (size_t)i * 512 * 512, proj_b + i * 512,
            h, rs_attn + i, h, nullptr, 512, 512, 512, 0);
        ln_bf16_kernel<<<512, 256, 0, stream>>>(h, ln2_g + i * 512, ln2_b + i * 512, xbuf_bf);
        gemm_mfma<<<dim3(32, 8), 256, 0, stream>>>(
            xbuf_bf, mlp_w1 + (size_t)i * 512 * 2048, mlp_b1 + i * 2048,
            nullptr, nullptr, nullptr, mbuf_bf, 512, 2048, 512, 1);
        gemm_mfma<<<dim3(8, 8), 256, 0, stream>>>(
            mbuf_bf, mlp_w2 + (size_t)i * 2048 * 512, mlp_b2 + i * 512,
            h, rs_mlp + i, h, nullptr, 512, 512, 2048, 0);
    }

    head_kernel<<<512, 256, 0, stream>>>(h, head_g, head_b, head_w, head_bs, out);
}

// Round 3
// 749.753 us; speedup vs baseline: 2.6550x; 1.3893x over previous
//
#include <hip/hip_runtime.h>
#include <math.h>

#define EPS 1e-5f

typedef __attribute__((ext_vector_type(8))) short short8;
typedef __attribute__((ext_vector_type(4))) float f32x4;

__device__ __forceinline__ short f2bf(float f) {
    unsigned u = __float_as_uint(f);
    u += 0x7fffu + ((u >> 16) & 1u);
    return (short)(u >> 16);
}
__device__ __forceinline__ float bf2f(short s) {
    return __uint_as_float(((unsigned)(unsigned short)s) << 16);
}
// async global->LDS, 16 bytes per lane; LDS dest must be wave-uniform base + lane*16
__device__ __forceinline__ void async16(const void* g, void* l) {
    __builtin_amdgcn_global_load_lds(
        (const __attribute__((address_space(1))) unsigned*)g,
        (__attribute__((address_space(3))) unsigned*)l, 16, 0, 0);
}

// ---------------------------------------------------------------------------
__device__ __forceinline__ float block_reduce_sum_256(float v, float* red) {
    #pragma unroll
    for (int o = 32; o > 0; o >>= 1) v += __shfl_down(v, o, 64);
    __syncthreads();
    if ((threadIdx.x & 63) == 0) red[threadIdx.x >> 6] = v;
    __syncthreads();
    return red[0] + red[1] + red[2] + red[3];
}

// ---------------------------------------------------------------------------
// FiLM: gb[bt,1024] = z[bt,:] @ film_w[32,1024] + film_b
__global__ __launch_bounds__(256) void film_kernel(
    const float* __restrict__ z, const float* __restrict__ fw,
    const float* __restrict__ fb, float* __restrict__ gb) {
    int bt = blockIdx.x;
    __shared__ float zs[32];
    if (threadIdx.x < 32) zs[threadIdx.x] = z[bt * 32 + threadIdx.x];
    __syncthreads();
    for (int j = threadIdx.x; j < 1024; j += 256) {
        float acc = fb[j];
        #pragma unroll
        for (int k = 0; k < 32; k++) acc = fmaf(zs[k], fw[k * 1024 + j], acc);
        gb[bt * 1024 + j] = acc;
    }
}

// ---------------------------------------------------------------------------
// elementwise fp32 -> bf16 cast (conv weights already [N=512][K=576])
__global__ __launch_bounds__(256) void cvt_kernel(
    const float* __restrict__ src, short* __restrict__ dst, int n) {
    int i = blockIdx.x * 256 + threadIdx.x;
    if (i < n) dst[i] = f2bf(src[i]);
}

// ---------------------------------------------------------------------------
// transpose + cast: src fp32 [L][K][N] -> dst bf16 [L][N][K]
__global__ __launch_bounds__(256) void tcast_kernel(
    const float* __restrict__ src, short* __restrict__ dst, int K, int N) {
    __shared__ float tile[32][33];
    src += (size_t)blockIdx.z * K * N;
    dst += (size_t)blockIdx.z * N * K;
    int n0 = blockIdx.x * 32, k0 = blockIdx.y * 32;
    int lx = threadIdx.x & 31, ly = threadIdx.x >> 5;
    #pragma unroll
    for (int i = 0; i < 32; i += 8)
        tile[ly + i][lx] = src[(size_t)(k0 + ly + i) * N + n0 + lx];
    __syncthreads();
    #pragma unroll
    for (int i = 0; i < 32; i += 8)
        dst[(size_t)(n0 + ly + i) * K + k0 + lx] = f2bf(tile[lx][ly + i]);
}

// ---------------------------------------------------------------------------
// Conv as GEMM, m97-style 128x128 tile, BK=32. M=32768 tokens, N=512, K=576.
// A = inline im2col (bf16 into LDS), B = conv weights bf16 [N][K] via async lds.
// LDS rows: 32 bf16 = 64 B, unpadded -> conflict-free ds_read_b128.
__global__ __launch_bounds__(256) void conv_gemm(
    const float* __restrict__ x, const short* __restrict__ wbf,
    const float* __restrict__ cb, short* __restrict__ tok) {
    __shared__ short As[128 * 32];
    __shared__ short Bs[128 * 32];
    int tid = threadIdx.x;
    int n0 = blockIdx.x * 128, m0 = blockIdx.y * 128;
    int wave = tid >> 6, lane = tid & 63, quad = lane >> 4, l16 = lane & 15;
    int wm = wave & 1, wn = wave >> 1;

    f32x4 acc[4][4];
    #pragma unroll
    for (int mt = 0; mt < 4; mt++)
        #pragma unroll
        for (int nt = 0; nt < 4; nt++) acc[mt][nt] = (f32x4){0.f, 0.f, 0.f, 0.f};

    for (int k0 = 0; k0 < 576; k0 += 32) {
        // B: 128 rows x 32 k = 512 x 16B chunks, 2 per thread (wave-contiguous)
        #pragma unroll
        for (int e = 0; e < 2; e++) {
            int c = e * 256 + tid;
            async16(wbf + (size_t)(n0 + (c >> 2)) * 576 + k0 + (c & 3) * 8,
                    (short*)Bs + c * 8);
        }
        // A: inline im2col, 8 consecutive k per chunk = 8 consecutive x floats
        #pragma unroll
        for (int e = 0; e < 2; e++) {
            int c = e * 256 + tid;
            int row = m0 + (c >> 2);
            int ks = (k0 >> 3) + (c & 3);          // k/8: = ch*24 + kt*8 + ph
            int ch = ks / 24, r = ks - ch * 24, kt = r >> 3, ph = r & 7;
            int bt = row >> 6, nn = row & 63, hn = nn >> 3, wn2 = nn & 7;
            int b = bt >> 5, t = bt & 31, tt = t + kt - 2;
            short8 v8;
            if (tt >= 0) {
                const float* xp = x + (((size_t)(b * 32 + tt) * 3 + ch) << 12)
                                    + (hn * 8 + ph) * 64 + wn2 * 8;
                float4 f0 = *(const float4*)xp;
                float4 f1 = *(const float4*)(xp + 4);
                v8 = (short8){f2bf(f0.x), f2bf(f0.y), f2bf(f0.z), f2bf(f0.w),
                              f2bf(f1.x), f2bf(f1.y), f2bf(f1.z), f2bf(f1.w)};
            } else {
                v8 = (short8){0, 0, 0, 0, 0, 0, 0, 0};
            }
            *(short8*)((short*)As + c * 8) = v8;
        }
        __syncthreads();
        short8 af[4], bfr[4];
        #pragma unroll
        for (int mt = 0; mt < 4; mt++)
            af[mt] = *(const short8*)&As[(wm * 64 + mt * 16 + l16) * 32 + quad * 8];
        #pragma unroll
        for (int nt = 0; nt < 4; nt++)
            bfr[nt] = *(const short8*)&Bs[(wn * 64 + nt * 16 + l16) * 32 + quad * 8];
        #pragma unroll
        for (int mt = 0; mt < 4; mt++)
            #pragma unroll
            for (int nt = 0; nt < 4; nt++)
                acc[mt][nt] = __builtin_amdgcn_mfma_f32_16x16x32_bf16(
                    af[mt], bfr[nt], acc[mt][nt], 0, 0, 0);
        __syncthreads();
    }
    #pragma unroll
    for (int mt = 0; mt < 4; mt++)
        #pragma unroll
        for (int nt = 0; nt < 4; nt++)
            #pragma unroll
            for (int reg = 0; reg < 4; reg++) {
                int m = m0 + wm * 64 + mt * 16 + quad * 4 + reg;
                int n = n0 + wn * 64 + nt * 16 + l16;
                tok[(size_t)m * 512 + n] = f2bf(acc[mt][nt][reg] + cb[n]);
            }
}

// ---------------------------------------------------------------------------
// tok_post: per (b,t): LN over 512 ch for each of 64 tokens + FiLM + mean -> h
__global__ __launch_bounds__(256) void tok_post(
    const short* __restrict__ tok, const float* __restrict__ tg,
    const float* __restrict__ tb, const float* __restrict__ gb,
    float* __restrict__ h) {
    __shared__ float mu_s[64], inv_s[64];
    __shared__ float red[4][512];
    int bt = blockIdx.x, tid = threadIdx.x;
    int wave = tid >> 6, lane = tid & 63;
    // pass 1: per-token stats (4 lanes per token, 128 ch each)
    {
        int tokn = wave * 16 + (lane >> 2), part = lane & 3;
        const short* p = tok + (size_t)(bt * 64 + tokn) * 512 + part * 128;
        float s = 0.f, ss = 0.f;
        #pragma unroll
        for (int i = 0; i < 16; i++) {
            short8 v = *(const short8*)(p + i * 8);
            #pragma unroll
            for (int j = 0; j < 8; j++) {
                float f = bf2f(v[j]);
                s += f; ss += f * f;
            }
        }
        s += __shfl_xor(s, 1, 64); ss += __shfl_xor(ss, 1, 64);
        s += __shfl_xor(s, 2, 64); ss += __shfl_xor(ss, 2, 64);
        if (part == 0) {
            float mu = s * (1.f / 512.f);
            float var = ss * (1.f / 512.f) - mu * mu;
            mu_s[tokn] = mu;
            inv_s[tokn] = rsqrtf(var + EPS);
        }
    }
    __syncthreads();
    // pass 2: accumulate sum over tokens of (v-mu)*inv per channel
    float hacc[8] = {0.f, 0.f, 0.f, 0.f, 0.f, 0.f, 0.f, 0.f};
    int c0 = lane * 8;
    for (int it = 0; it < 16; it++) {
        int n = it * 4 + wave;
        float mu = mu_s[n], inv = inv_s[n];
        short8 v = *(const short8*)(tok + (size_t)(bt * 64 + n) * 512 + c0);
        #pragma unroll
        for (int j = 0; j < 8; j++) hacc[j] += (bf2f(v[j]) - mu) * inv;
    }
    #pragma unroll
    for (int j = 0; j < 8; j++) red[wave][c0 + j] = hacc[j];
    __syncthreads();
    #pragma unroll
    for (int cc = 0; cc < 2; cc++) {
        int c = tid + cc * 256;
        float S = red[0][c] + red[1][c] + red[2][c] + red[3][c];
        float G  = 1.f + 0.5f * gb[bt * 1024 + c];
        float Be = 0.5f * gb[bt * 1024 + 512 + c];
        h[bt * 512 + c] = G * (tg[c] * (S * (1.f / 64.f)) + tb[c]) + Be;
    }
}

// ---------------------------------------------------------------------------
// LayerNorm over D=512, bf16 output. 1 block per token.
__global__ __launch_bounds__(256) void ln_bf16_kernel(
    const float* __restrict__ in, const float* __restrict__ g,
    const float* __restrict__ bb, short* __restrict__ out) {
    __shared__ float red[8];
    int token = blockIdx.x, tid = threadIdx.x;
    float v0 = in[token * 512 + tid], v1 = in[token * 512 + tid + 256];
    float s  = block_reduce_sum_256(v0 + v1, red);
    float ss = block_reduce_sum_256(v0 * v0 + v1 * v1, red);
    float mu = s * (1.f / 512.f);
    float var = ss * (1.f / 512.f) - mu * mu;
    float inv = rsqrtf(var + EPS);
    out[token * 512 + tid]       = f2bf((v0 - mu) * inv * g[tid] + bb[tid]);
    out[token * 512 + tid + 256] = f2bf((v1 - mu) * inv * g[tid + 256] + bb[tid + 256]);
}

// ---------------------------------------------------------------------------
// bf16 MFMA GEMM, 64x64 tile, BK=32, A[M][K] bf16, B[N][K] bf16, async staging.
// act: 0=none, 1=exact GELU. res: out = res + (*resScale)*val.
__global__ __launch_bounds__(256) void gemm64(
    const short* __restrict__ A, const short* __restrict__ B,
    const float* __restrict__ bias, const float* __restrict__ res,
    const float* __restrict__ resScale, float* __restrict__ outf,
    short* __restrict__ outb, int N, int K, int act) {
    __shared__ short As[64 * 32];
    __shared__ short Bs[64 * 32];
    int tid = threadIdx.x;
    int n0 = blockIdx.x * 64, m0 = blockIdx.y * 64;
    int wave = tid >> 6, lane = tid & 63, quad = lane >> 4, l16 = lane & 15;
    int wm = wave & 1, wn = wave >> 1;
    f32x4 acc[2][2];
    #pragma unroll
    for (int mt = 0; mt < 2; mt++)
        #pragma unroll
        for (int nt = 0; nt < 2; nt++) acc[mt][nt] = (f32x4){0.f, 0.f, 0.f, 0.f};

    for (int k0 = 0; k0 < K; k0 += 32) {
        int c = tid;    // 256 chunks per matrix, 1 per thread, wave-contiguous
        async16(A + (size_t)(m0 + (c >> 2)) * K + k0 + (c & 3) * 8, (short*)As + c * 8);
        async16(B + (size_t)(n0 + (c >> 2)) * K + k0 + (c & 3) * 8, (short*)Bs + c * 8);
        __syncthreads();
        short8 af[2], bfr[2];
        #pragma unroll
        for (int mt = 0; mt < 2; mt++)
            af[mt] = *(const short8*)&As[(wm * 32 + mt * 16 + l16) * 32 + quad * 8];
        #pragma unroll
        for (int nt = 0; nt < 2; nt++)
            bfr[nt] = *(const short8*)&Bs[(wn * 32 + nt * 16 + l16) * 32 + quad * 8];
        #pragma unroll
        for (int mt = 0; mt < 2; mt++)
            #pragma unroll
            for (int nt = 0; nt < 2; nt++)
                acc[mt][nt] = __builtin_amdgcn_mfma_f32_16x16x32_bf16(
                    af[mt], bfr[nt], acc[mt][nt], 0, 0, 0);
        __syncthreads();
    }

    float rs = resScale ? *resScale : 0.f;
    #pragma unroll
    for (int mt = 0; mt < 2; mt++)
        #pragma unroll
        for (int nt = 0; nt < 2; nt++)
            #pragma unroll
            for (int reg = 0; reg < 4; reg++) {
                int m = m0 + wm * 32 + mt * 16 + quad * 4 + reg;
                int n = n0 + wn * 32 + nt * 16 + l16;
                float v = acc[mt][nt][reg] + bias[n];
                if (act == 1) v = 0.5f * v * (1.f + erff(v * 0.70710678118f));
                if (res) v = res[(size_t)m * N + n] + rs * v;
                if (outf) outf[(size_t)m * N + n] = v;
                if (outb) outb[(size_t)m * N + n] = f2bf(v);
            }
}

// ---------------------------------------------------------------------------
// Attention for one (b, head). T=32, DH=64, causal, RoPE. fp32 in, bf16 out.
__global__ __launch_bounds__(256) void attn_kernel(
    const float* __restrict__ kqv, short* __restrict__ yv) {
    __shared__ float qs[32][64], ks[32][64], vs[32][64];
    __shared__ float qr[32][64], kr[32][64];
    __shared__ float att[32][32];
    int blk = blockIdx.x;
    int b = blk >> 3, hh = blk & 7;
    int tid = threadIdx.x;

    for (int idx = tid; idx < 2048; idx += 256) {
        int t = idx >> 6, d = idx & 63;
        const float* base = kqv + (size_t)(b * 32 + t) * 1536 + hh * 64 + d;
        ks[t][d] = base[0];
        qs[t][d] = base[512];
        vs[t][d] = base[1024];
    }
    __syncthreads();
    const float lnb = logf(10000.f) / 32.f;
    for (int idx = tid; idx < 2048; idx += 256) {
        int t = idx >> 6, d = idx & 63;
        int j = d & 31;
        float ang = (float)t * expf(-(float)j * lnb);
        float sv = sinf(ang), cv = cosf(ang);
        float qv = qs[t][d], kv = ks[t][d];
        float qo = qs[t][d ^ 32], ko = ks[t][d ^ 32];
        float rq = (d < 32) ? -qo : qo;
        float rk = (d < 32) ? -ko : ko;
        qr[t][d] = qv * cv + rq * sv;
        kr[t][d] = kv * cv + rk * sv;
    }
    __syncthreads();
    #pragma unroll
    for (int l = 0; l < 4; l++) {
        int idx = l * 256 + tid;
        int qt = idx >> 5, kt2 = idx & 31;
        float s;
        if (kt2 > qt) {
            s = -1e30f;
        } else {
            float a = 0.f;
            #pragma unroll
            for (int d = 0; d < 64; d++) a = fmaf(qr[qt][d], kr[kt2][d], a);
            s = a * 0.125f;
        }
        att[qt][kt2] = s;
    }
    __syncthreads();
    if (tid < 32) {
        float m = -1e30f;
        #pragma unroll
        for (int k = 0; k < 32; k++) m = fmaxf(m, att[tid][k]);
        float sum = 0.f;
        #pragma unroll
        for (int k = 0; k < 32; k++) {
            float e = expf(att[tid][k] - m);
            att[tid][k] = e;
            sum += e;
        }
        float inv = 1.f / sum;
        #pragma unroll
        for (int k = 0; k < 32; k++) att[tid][k] *= inv;
    }
    __syncthreads();
    for (int idx = tid; idx < 2048; idx += 256) {
        int t = idx >> 6, d = idx & 63;
        float a = 0.f;
        #pragma unroll
        for (int k = 0; k < 32; k++) a = fmaf(att[t][k], vs[k][d], a);
        yv[(size_t)(b * 32 + t) * 512 + hh * 64 + d] = f2bf(a);
    }
}

// ---------------------------------------------------------------------------
__global__ __launch_bounds__(256) void head_kernel(
    const float* __restrict__ h, const float* __restrict__ g,
    const float* __restrict__ bb, const float* __restrict__ w,
    const float* __restrict__ bias0, float* __restrict__ out) {
    __shared__ float red[8];
    int token = blockIdx.x, tid = threadIdx.x;
    float v0 = h[token * 512 + tid], v1 = h[token * 512 + tid + 256];
    float s  = block_reduce_sum_256(v0 + v1, red);
    float ss = block_reduce_sum_256(v0 * v0 + v1 * v1, red);
    float mu = s * (1.f / 512.f);
    float var = ss * (1.f / 512.f) - mu * mu;
    float inv = rsqrtf(var + EPS);
    float n0 = (v0 - mu) * inv * g[tid] + bb[tid];
    float n1 = (v1 - mu) * inv * g[tid + 256] + bb[tid + 256];
    float dot = block_reduce_sum_256(n0 * w[tid] + n1 * w[tid + 256], red);
    if (tid == 0) out[token] = dot + bias0[0];
}

// ---------------------------------------------------------------------------
extern "C" void kernel_launch(void* const* d_in, const int* in_sizes, int n_in,
                              void* d_out, int out_size, void* d_ws, size_t ws_size,
                              hipStream_t stream) {
    const float* x       = (const float*)d_in[0];
    const float* z       = (const float*)d_in[1];
    const float* conv_w  = (const float*)d_in[2];
    const float* conv_b  = (const float*)d_in[3];
    const float* tok_g   = (const float*)d_in[4];
    const float* tok_b   = (const float*)d_in[5];
    const float* film_w  = (const float*)d_in[6];
    const float* film_b  = (const float*)d_in[7];
    const float* ln1_g   = (const float*)d_in[8];
    const float* ln1_b   = (const float*)d_in[9];
    const float* kqv_w   = (const float*)d_in[10];
    const float* kqv_b   = (const float*)d_in[11];
    const float* proj_w  = (const float*)d_in[12];
    const float* proj_b  = (const float*)d_in[13];
    const float* ln2_g   = (const float*)d_in[14];
    const float* ln2_b   = (const float*)d_in[15];
    const float* mlp_w1  = (const float*)d_in[16];
    const float* mlp_b1  = (const float*)d_in[17];
    const float* mlp_w2  = (const float*)d_in[18];
    const float* mlp_b2  = (const float*)d_in[19];
    const float* rs_attn = (const float*)d_in[20];
    const float* rs_mlp  = (const float*)d_in[21];
    const float* head_g  = (const float*)d_in[22];
    const float* head_b  = (const float*)d_in[23];
    const float* head_w  = (const float*)d_in[24];
    const float* head_bs = (const float*)d_in[25];
    float* out = (float*)d_out;

    float* ws = (float*)d_ws;
    float* gb = ws;                    // 512*1024 f
    float* h  = gb + 524288;           // 512*512 f
    float* kqvb = h + 262144;          // 512*1536 f
    short* sb = (short*)(kqvb + 786432);
    short* wbf   = sb;                 // 294912
    short* kqvT  = wbf   + 294912;     // 6*1536*512 = 4718592
    short* projT = kqvT  + 4718592;    // 6*512*512  = 1572864
    short* mlp1T = projT + 1572864;    // 6*2048*512 = 6291456
    short* mlp2T = mlp1T + 6291456;    // 6*512*2048 = 6291456
    short* tokb  = mlp2T + 6291456;    // 32768*512  = 16777216
    short* xbuf  = tokb  + 16777216;   // 512*512
    short* yvb   = xbuf  + 262144;     // 512*512
    short* mbuf  = yvb   + 262144;     // 512*2048
    // total ~ 6.3 MB (f) + ~74 MB (sh) ≈ 80 MB

    film_kernel<<<512, 256, 0, stream>>>(z, film_w, film_b, gb);
    cvt_kernel<<<1152, 256, 0, stream>>>(conv_w, wbf, 294912);
    tcast_kernel<<<dim3(48, 16, 6), 256, 0, stream>>>(kqv_w, kqvT, 512, 1536);
    tcast_kernel<<<dim3(16, 16, 6), 256, 0, stream>>>(proj_w, projT, 512, 512);
    tcast_kernel<<<dim3(64, 16, 6), 256, 0, stream>>>(mlp_w1, mlp1T, 512, 2048);
    tcast_kernel<<<dim3(16, 64, 6), 256, 0, stream>>>(mlp_w2, mlp2T, 2048, 512);

    conv_gemm<<<dim3(4, 256), 256, 0, stream>>>(x, wbf, conv_b, tokb);
    tok_post<<<512, 256, 0, stream>>>(tokb, tok_g, tok_b, gb, h);

    for (int i = 0; i < 6; i++) {
        ln_bf16_kernel<<<512, 256, 0, stream>>>(h, ln1_g + i * 512, ln1_b + i * 512, xbuf);
        gemm64<<<dim3(24, 8), 256, 0, stream>>>(
            xbuf, kqvT + (size_t)i * 1536 * 512, kqv_b + i * 1536,
            nullptr, nullptr, kqvb, nullptr, 1536, 512, 0);
        attn_kernel<<<128, 256, 0, stream>>>(kqvb, yvb);
        gemm64<<<dim3(8, 8), 256, 0, stream>>>(
            yvb, projT + (size_t)i * 512 * 512, proj_b + i * 512,
            h, rs_attn + i, h, nullptr, 512, 512, 0);
        ln_bf16_kernel<<<512, 256, 0, stream>>>(h, ln2_g + i * 512, ln2_b + i * 512, xbuf);
        gemm64<<<dim3(32, 8), 256, 0, stream>>>(
            xbuf, mlp1T + (size_t)i * 2048 * 512, mlp_b1 + i * 2048,
            nullptr, nullptr, nullptr, mbuf, 2048, 512, 1);
        gemm64<<<dim3(8, 8), 256, 0, stream>>>(
            mbuf, mlp2T + (size_t)i * 512 * 2048, mlp_b2 + i * 512,
            h, rs_mlp + i, h, nullptr, 512, 2048, 0);
    }

    head_kernel<<<512, 256, 0, stream>>>(h, head_g, head_b, head_w, head_bs, out);
}